// Round 1
// baseline (653.424 us; speedup 1.0000x reference)
//
#include <hip/hip_runtime.h>

// Lattice: 32^4 sites, F=8 channels, complex 3-vectors, 4 link directions.
// x:  (8, 32,32,32,32, 3)  complex (split re/im arrays)
// U:  (4, 32,32,32,32, 3,3) complex (split re/im arrays)
// out: (2, 8, 32,32,32,32, 3) float32  [re block then im block]
//
// This version: one thread = 4 consecutive t-sites. Every global access is a
// 16B-aligned dwordx4 (x-block: 3xfloat4, U-block: 9xfloat4, store: 3xfloat4),
// and a channel's loads are issued back-to-back before use -> high MLP per wave.

#define V (32*32*32*32)          // 1,048,576 sites
#define V3 (V*3)
#define SX (32*32*32)            // +1 in x
#define SY (32*32)               // +1 in y
#define SZ 32                    // +1 in z
// t stride = 1

typedef float f4 __attribute__((ext_vector_type(4)));

// 12 consecutive floats (4 sites x 3 colors), base guaranteed 16B-aligned
__device__ __forceinline__ void load12(const float* __restrict__ g, long fidx, float* d) {
    const f4* q = reinterpret_cast<const f4*>(g + fidx);
    f4 a = q[0], b = q[1], c = q[2];
#pragma unroll
    for (int k = 0; k < 4; ++k) { d[k] = a[k]; d[4+k] = b[k]; d[8+k] = c[k]; }
}

// 36 consecutive floats (4 sites x 3x3), base guaranteed 16B-aligned
__device__ __forceinline__ void load36(const float* __restrict__ g, long fidx, float* d) {
    const f4* q = reinterpret_cast<const f4*>(g + fidx);
#pragma unroll
    for (int m = 0; m < 9; ++m) {
        f4 v = q[m];
#pragma unroll
        for (int k = 0; k < 4; ++k) d[4*m + k] = v[k];
    }
}

__device__ __forceinline__ void store12(float* __restrict__ g, long fidx, const float* d) {
    f4* q = reinterpret_cast<f4*>(g + fidx);
    f4 a, b, c;
#pragma unroll
    for (int k = 0; k < 4; ++k) { a[k] = d[k]; b[k] = d[4+k]; c[k] = d[8+k]; }
    __builtin_nontemporal_store(a, q + 0);   // output never re-read: keep LLC for inputs
    __builtin_nontemporal_store(b, q + 1);
    __builtin_nontemporal_store(c, q + 2);
}

// 4-site complex matvec: y_i = sc * op(U_i) v_i   (op = dag ? conj-transpose : id)
template<bool DAG>
__device__ __forceinline__ void matvec4(const float* Ur, const float* Ui,
                                        const float* vr, const float* vi,
                                        float sc, float* yr, float* yi) {
#pragma unroll
    for (int i = 0; i < 4; ++i) {
#pragma unroll
        for (int a = 0; a < 3; ++a) {
            float ar = 0.f, ai = 0.f;
#pragma unroll
            for (int b = 0; b < 3; ++b) {
                float ur = DAG ? Ur[9*i + b*3 + a] : Ur[9*i + a*3 + b];
                float ui = DAG ? Ui[9*i + b*3 + a] : Ui[9*i + a*3 + b];
                if (DAG) { ar += ur*vr[3*i+b] + ui*vi[3*i+b];
                           ai += ur*vi[3*i+b] - ui*vr[3*i+b]; }
                else     { ar += ur*vr[3*i+b] - ui*vi[3*i+b];
                           ai += ur*vi[3*i+b] + ui*vr[3*i+b]; }
            }
            yr[3*i+a] = sc*ar; yi[3*i+a] = sc*ai;
        }
    }
}

// one simple hop channel: out_f(s..s+3) = sc * op(U_mu(su..su+3)) x_f(sv..sv+3)
template<bool DAG>
__device__ __forceinline__ void channel(const float* __restrict__ xr, const float* __restrict__ xi,
                                        const float* __restrict__ Urg, const float* __restrict__ Uig,
                                        float* __restrict__ outr, float* __restrict__ outi,
                                        int f, int mu, int su, int sv, int s, float sc) {
    float Ur[36], Ui[36], vr[12], vi[12], yr[12], yi[12];
    const long ub = (long)mu * V * 9 + (long)su * 9;
    const long vb = (long)f * V3 + (long)sv * 3;
    load36(Urg, ub, Ur); load36(Uig, ub, Ui);
    load12(xr, vb, vr);  load12(xi, vb, vi);
    matvec4<DAG>(Ur, Ui, vr, vi, sc, yr, yi);
    const long ob = (long)f * V3 + (long)s * 3;
    store12(outr, ob, yr); store12(outi, ob, yi);
}

__global__ __launch_bounds__(256) void transport_kernel(
        const float* __restrict__ xr, const float* __restrict__ xi,
        const float* __restrict__ Urg, const float* __restrict__ Uig,
        float* __restrict__ outr, float* __restrict__ outi) {
    const int g = blockIdx.x * blockDim.x + threadIdx.x;   // g < V/4
    const int s = g << 2;                                  // base site; t0 = s&31 in {0,4,...,28}
    const int t0 = s & 31;
    const int z  = (s >> 5)  & 31;
    const int y  = (s >> 10) & 31;
    const int x  = (s >> 15) & 31;

    // block-uniform neighbor bases (all shifts are multiples of 4 sites -> stay 16B-aligned)
    const int s_xp   = s + ((x == 31) ? -(31*SX) : SX);
    const int s_xm   = s + ((x == 0)  ?  (31*SX) : -SX);
    const int s_yp   = s + ((y == 31) ? -(31*SY) : SY);
    const int s_ym   = s + ((y == 0)  ?  (31*SY) : -SY);
    const int s_zp   = s + ((z == 31) ? -(31*SZ) : SZ);
    const int s_xpyp = s_yp + ((x == 31) ? -(31*SX) : SX);
    const int s_t1   = (t0 == 28) ? (s - 28) : (s + 4);    // next t-block base (wraps to t=0)

    const float eta1 = (x & 1) ? -1.f : 1.f;               // (-1)^x0
    const float eta2 = ((x + y) & 1) ? -1.f : 1.f;         // (-1)^(x0+x1)
    const float eta3 = ((x + y + z) & 1) ? -1.f : 1.f;     // (-1)^(x0+x1+x2)

    // ch0: identity copy
    {
        float vr[12], vi[12];
        const long vb = 0L * V3 + (long)s * 3;
        load12(xr, vb, vr); load12(xi, vb, vi);
        store12(outr, vb, vr); store12(outi, vb, vi);
    }

    // ch1: (0,+1): U0(x) x1(x+xhat), eta0 = 1
    channel<false>(xr, xi, Urg, Uig, outr, outi, 1, 0, s, s_xp, s, 1.f);

    // ch5: (0,-1): U0^dag(x-xhat) x5(x-xhat), eta0 = 1
    channel<true >(xr, xi, Urg, Uig, outr, outi, 5, 0, s_xm, s_xm, s, 1.f);

    // ch2: (1,+1): eta1(x) U1(x) x2(x+yhat)
    channel<false>(xr, xi, Urg, Uig, outr, outi, 2, 1, s, s_yp, s, eta1);

    // ch6: (1,-1): eta1(x-yhat) = eta1(x); U1^dag(x-yhat) x6(x-yhat)
    channel<true >(xr, xi, Urg, Uig, outr, outi, 6, 1, s_ym, s_ym, s, eta1);

    // ch3: (2,+1): eta2(x) U2(x) x3(x+zhat)
    channel<false>(xr, xi, Urg, Uig, outr, outi, 3, 2, s, s_zp, s, eta2);

    // ch4: (3,+1): eta3(x) U3(x) x4(x+that) — t-hop crosses the 4-site block
    {
        float Ur[36], Ui[36], vr[12], vi[12], yr[12], yi[12];
        float b0r[12], b0i[12], b1r[12], b1i[12];
        const long ub  = 3L * (long)V * 9 + (long)s * 9;
        const long vb0 = 4L * V3 + (long)s * 3;
        const long vb1 = 4L * V3 + (long)s_t1 * 3;
        load36(Urg, ub, Ur); load36(Uig, ub, Ui);
        load12(xr, vb0, b0r); load12(xi, vb0, b0i);
        load12(xr, vb1, b1r); load12(xi, vb1, b1i);
        // site i needs x4 at t+i+1: i<3 -> own block pos i+1; i==3 -> next block pos 0
#pragma unroll
        for (int k = 0; k < 9; ++k) { vr[k] = b0r[k+3]; vi[k] = b0i[k+3]; }
#pragma unroll
        for (int k = 0; k < 3; ++k) { vr[9+k] = b1r[k]; vi[9+k] = b1i[k]; }
        matvec4<false>(Ur, Ui, vr, vi, eta3, yr, yi);
        const long ob = 4L * V3 + (long)s * 3;
        store12(outr, ob, yr); store12(outi, ob, yi);
    }

    // ch7: (0,+1)(1,+1): eta1(x) * U1(x) @ U0(x+yhat) @ x7(x+xhat+yhat)
    {
        float Ur[36], Ui[36], vr[12], vi[12], gr[12], gi[12], yr[12], yi[12];
        const long ub0 = 0L * (long)V * 9 + (long)s_yp * 9;
        const long vb  = 7L * V3 + (long)s_xpyp * 3;
        load36(Urg, ub0, Ur); load36(Uig, ub0, Ui);
        load12(xr, vb, vr);   load12(xi, vb, vi);
        matvec4<false>(Ur, Ui, vr, vi, 1.f, gr, gi);          // g = U0(x+yhat) x7
        const long ub1 = 1L * (long)V * 9 + (long)s * 9;
        load36(Urg, ub1, Ur); load36(Uig, ub1, Ui);           // reload U1(x) (L1/L2-hot)
        matvec4<false>(Ur, Ui, gr, gi, eta1, yr, yi);          // y = eta1 U1(x) g
        const long ob = 7L * V3 + (long)s * 3;
        store12(outr, ob, yr); store12(outi, ob, yi);
    }
}

extern "C" void kernel_launch(void* const* d_in, const int* in_sizes, int n_in,
                              void* d_out, int out_size, void* d_ws, size_t ws_size,
                              hipStream_t stream) {
    const float* xr  = (const float*)d_in[0];
    const float* xi  = (const float*)d_in[1];
    const float* Urg = (const float*)d_in[2];
    const float* Uig = (const float*)d_in[3];
    float* outr = (float*)d_out;
    float* outi = (float*)d_out + (long)8 * V3;   // imag block after real block

    const int block = 256;
    const int grid  = (V / 4) / block;            // 1024 blocks, one thread = 4 t-sites
    transport_kernel<<<grid, block, 0, stream>>>(xr, xi, Urg, Uig, outr, outi);
}

// Round 2
// 541.357 us; speedup vs baseline: 1.2070x; 1.2070x over previous
//
#include <hip/hip_runtime.h>

// Lattice: 32^4 sites, F=8 channels, complex 3-vectors, 4 link directions.
// x:  (8, 32,32,32,32, 3)  complex (split re/im arrays)
// U:  (4, 32,32,32,32, 3,3) complex (split re/im arrays)
// out: (2, 8, 32,32,32,32, 3) float32  [re block then im block]
//
// Round 2: back to 1 site/thread (perfect dword coalescing, low VGPR),
// plus explicit double-buffered software pipeline across channels:
// channel k+1's U and x loads are issued before channel k's compute, so
// each wave keeps a full channel's loads (~800 B) in flight at all times.
// Plain stores (round-1's nontemporal stores caused partial-line RMW:
// WRITE_SIZE 196->362 MB). XCD-chunked block swizzle for L2 locality of
// the x/U neighbor re-read streams.

#define V (32*32*32*32)          // 1,048,576 sites
#define V3 (V*3)
#define SX (32*32*32)            // +1 in x
#define SY (32*32)               // +1 in y
#define SZ 32                    // +1 in z
// t stride = 1

struct U9 { float r[9]; float i[9]; };
struct C3 { float r[3]; float i[3]; };

__device__ __forceinline__ void load_vec(const float* __restrict__ xr,
                                         const float* __restrict__ xi,
                                         int f, int s, C3& v) {
    long b = (long)f * V3 + (long)s * 3;
    v.r[0] = xr[b+0]; v.r[1] = xr[b+1]; v.r[2] = xr[b+2];
    v.i[0] = xi[b+0]; v.i[1] = xi[b+1]; v.i[2] = xi[b+2];
}

__device__ __forceinline__ void load_U(const float* __restrict__ Urg,
                                       const float* __restrict__ Uig,
                                       int mu, int s, U9& U) {
    long b = (long)mu * (long)V * 9 + (long)s * 9;
#pragma unroll
    for (int k = 0; k < 9; ++k) { U.r[k] = Urg[b+k]; U.i[k] = Uig[b+k]; }
}

// y = sc * op(U) v ; op = conj-transpose if DAG
template<bool DAG>
__device__ __forceinline__ void matvec(const U9& U, const C3& v, float sc, C3& y) {
#pragma unroll
    for (int a = 0; a < 3; ++a) {
        float ar = 0.f, ai = 0.f;
#pragma unroll
        for (int b = 0; b < 3; ++b) {
            float ur = DAG ? U.r[b*3+a] : U.r[a*3+b];
            float ui = DAG ? U.i[b*3+a] : U.i[a*3+b];
            if (DAG) { ar += ur*v.r[b] + ui*v.i[b];
                       ai += ur*v.i[b] - ui*v.r[b]; }
            else     { ar += ur*v.r[b] - ui*v.i[b];
                       ai += ur*v.i[b] + ui*v.r[b]; }
        }
        y.r[a] = sc*ar; y.i[a] = sc*ai;
    }
}

__device__ __forceinline__ void store_out(float* __restrict__ outr,
                                          float* __restrict__ outi,
                                          int f, int s, const C3& y) {
    long b = (long)f * V3 + (long)s * 3;
    outr[b+0] = y.r[0]; outr[b+1] = y.r[1]; outr[b+2] = y.r[2];
    outi[b+0] = y.i[0]; outi[b+1] = y.i[1]; outi[b+2] = y.i[2];
}

__global__ __launch_bounds__(256) void transport_kernel(
        const float* __restrict__ xr, const float* __restrict__ xi,
        const float* __restrict__ Urg, const float* __restrict__ Uig,
        float* __restrict__ outr, float* __restrict__ outi) {
    // XCD-chunked remap: default dispatch round-robins consecutive blocks
    // across the 8 XCDs; remap so each XCD sweeps a contiguous 1/8 slab
    // (neighbor re-read streams then lag <= ~2.3 MB within one XCD's L2).
    // gridDim.x = 4096, divisible by 8 -> bijective.
    const int bid  = blockIdx.x;
    const int swz  = (bid & 7) * (int)(gridDim.x >> 3) + (bid >> 3);
    const int s    = swz * 256 + threadIdx.x;

    const int t = s & 31;
    const int z = (s >> 5) & 31;
    const int y = (s >> 10) & 31;
    const int x = (s >> 15) & 31;

    const int s_xp   = s + ((x == 31) ? -(31*SX) : SX);
    const int s_xm   = s + ((x == 0)  ?  (31*SX) : -SX);
    const int s_yp   = s + ((y == 31) ? -(31*SY) : SY);
    const int s_ym   = s + ((y == 0)  ?  (31*SY) : -SY);
    const int s_zp   = s + ((z == 31) ? -(31*SZ) : SZ);
    const int s_tp   = s + ((t == 31) ? -31 : 1);
    const int s_xpyp = s_yp + ((x == 31) ? -(31*SX) : SX);

    const float eta1 = (x & 1) ? -1.f : 1.f;              // (-1)^x0
    const float eta2 = ((x + y) & 1) ? -1.f : 1.f;        // (-1)^(x0+x1)
    const float eta3 = ((x + y + z) & 1) ? -1.f : 1.f;    // (-1)^(x0+x1+x2)

    U9 Ua, Ub;
    C3 va, vb, yv, g;

    // ---- stage ch1 into A ----
    load_U(Urg, Uig, 0, s, Ua); load_vec(xr, xi, 1, s_xp, va);

    // ch0: identity (independent loads+store, overlaps ch1's latency)
    { C3 v0; load_vec(xr, xi, 0, s, v0); store_out(outr, outi, 0, s, v0); }

    // ---- stage ch2 into B; compute ch1 from A ----
    load_U(Urg, Uig, 1, s, Ub); load_vec(xr, xi, 2, s_yp, vb);
    matvec<false>(Ua, va, 1.f, yv);  store_out(outr, outi, 1, s, yv);

    // ---- stage ch3 into A; compute ch2 from B ----
    load_U(Urg, Uig, 2, s, Ua); load_vec(xr, xi, 3, s_zp, va);
    matvec<false>(Ub, vb, eta1, yv); store_out(outr, outi, 2, s, yv);

    // ---- stage ch4 into B; compute ch3 from A ----
    load_U(Urg, Uig, 3, s, Ub); load_vec(xr, xi, 4, s_tp, vb);
    matvec<false>(Ua, va, eta2, yv); store_out(outr, outi, 3, s, yv);

    // ---- stage ch5 into A; compute ch4 from B ----
    load_U(Urg, Uig, 0, s_xm, Ua); load_vec(xr, xi, 5, s_xm, va);
    matvec<false>(Ub, vb, eta3, yv); store_out(outr, outi, 4, s, yv);

    // ---- stage ch6 into B; compute ch5 (dag) from A ----
    load_U(Urg, Uig, 1, s_ym, Ub); load_vec(xr, xi, 6, s_ym, vb);
    matvec<true>(Ua, va, 1.f, yv);   store_out(outr, outi, 5, s, yv);

    // ---- stage ch7 inner (U0(x+yhat), x7(x+xhat+yhat)) into A; compute ch6 (dag) from B ----
    load_U(Urg, Uig, 0, s_yp, Ua); load_vec(xr, xi, 7, s_xpyp, va);
    matvec<true>(Ub, vb, eta1, yv);  store_out(outr, outi, 6, s, yv);

    // ---- stage ch7 outer (U1(x)) into B; compute ch7 ----
    load_U(Urg, Uig, 1, s, Ub);                       // L1/L2-hot (loaded for ch2)
    matvec<false>(Ua, va, 1.f, g);                    // g = U0(x+yhat) x7
    matvec<false>(Ub, g, eta1, yv);                   // y = eta1 * U1(x) g
    store_out(outr, outi, 7, s, yv);
}

extern "C" void kernel_launch(void* const* d_in, const int* in_sizes, int n_in,
                              void* d_out, int out_size, void* d_ws, size_t ws_size,
                              hipStream_t stream) {
    const float* xr  = (const float*)d_in[0];
    const float* xi  = (const float*)d_in[1];
    const float* Urg = (const float*)d_in[2];
    const float* Uig = (const float*)d_in[3];
    float* outr = (float*)d_out;
    float* outi = (float*)d_out + (long)8 * V3;   // imag block after real block

    const int block = 256;
    const int grid  = V / block;                  // 4096 blocks
    transport_kernel<<<grid, block, 0, stream>>>(xr, xi, Urg, Uig, outr, outi);
}

// Round 3
// 513.767 us; speedup vs baseline: 1.2718x; 1.0537x over previous
//
#include <hip/hip_runtime.h>

// Lattice: 32^4 sites, F=8 channels, complex 3-vectors, 4 link directions.
// x:  (8, 32,32,32,32, 3)  complex (split re/im arrays)
// U:  (4, 32,32,32,32, 3,3) complex (split re/im arrays)
// out: (2, 8, 32,32,32,32, 3) float32  [re block then im block]
//
// Round 3: round-0 structure (1 site/thread, natural block order — the
// XCD swizzle of round 2 regressed BW), but ALL stores deferred to a
// single terminal burst. Main body is read-only; outputs accumulate in
// 48 registers; an asm memory barrier pins the store burst at the end.
// Hypothesis under test: fine-grained R/W interleave (24 load dwords : 6
// store dwords, 8x per thread) causes HBM read<->write turnaround /row
// thrash, capping us at ~3.1 TB/s (49% of copy BW).

#define V (32*32*32*32)          // 1,048,576 sites
#define V3 (V*3)
#define SX (32*32*32)            // +1 in x
#define SY (32*32)               // +1 in y
#define SZ 32                    // +1 in z
// t stride = 1

struct U9 { float r[9]; float i[9]; };
struct C3 { float r[3]; float i[3]; };

__device__ __forceinline__ void load_vec(const float* __restrict__ xr,
                                         const float* __restrict__ xi,
                                         int f, int s, C3& v) {
    long b = (long)f * V3 + (long)s * 3;
    v.r[0] = xr[b+0]; v.r[1] = xr[b+1]; v.r[2] = xr[b+2];
    v.i[0] = xi[b+0]; v.i[1] = xi[b+1]; v.i[2] = xi[b+2];
}

__device__ __forceinline__ void load_U(const float* __restrict__ Urg,
                                       const float* __restrict__ Uig,
                                       int mu, int s, U9& U) {
    long b = (long)mu * (long)V * 9 + (long)s * 9;
#pragma unroll
    for (int k = 0; k < 9; ++k) { U.r[k] = Urg[b+k]; U.i[k] = Uig[b+k]; }
}

// y = sc * op(U) v ; op = conj-transpose if DAG
template<bool DAG>
__device__ __forceinline__ void matvec(const U9& U, const C3& v, float sc, C3& y) {
#pragma unroll
    for (int a = 0; a < 3; ++a) {
        float ar = 0.f, ai = 0.f;
#pragma unroll
        for (int b = 0; b < 3; ++b) {
            float ur = DAG ? U.r[b*3+a] : U.r[a*3+b];
            float ui = DAG ? U.i[b*3+a] : U.i[a*3+b];
            if (DAG) { ar += ur*v.r[b] + ui*v.i[b];
                       ai += ur*v.i[b] - ui*v.r[b]; }
            else     { ar += ur*v.r[b] - ui*v.i[b];
                       ai += ur*v.i[b] + ui*v.r[b]; }
        }
        y.r[a] = sc*ar; y.i[a] = sc*ai;
    }
}

__device__ __forceinline__ void store_out(float* __restrict__ outr,
                                          float* __restrict__ outi,
                                          int f, int s, const C3& y) {
    long b = (long)f * V3 + (long)s * 3;
    outr[b+0] = y.r[0]; outr[b+1] = y.r[1]; outr[b+2] = y.r[2];
    outi[b+0] = y.i[0]; outi[b+1] = y.i[1]; outi[b+2] = y.i[2];
}

__global__ __launch_bounds__(256) void transport_kernel(
        const float* __restrict__ xr, const float* __restrict__ xi,
        const float* __restrict__ Urg, const float* __restrict__ Uig,
        float* __restrict__ outr, float* __restrict__ outi) {
    const int s = blockIdx.x * blockDim.x + threadIdx.x;

    const int t = s & 31;
    const int z = (s >> 5) & 31;
    const int y = (s >> 10) & 31;
    const int x = (s >> 15) & 31;

    const int s_xp   = s + ((x == 31) ? -(31*SX) : SX);
    const int s_xm   = s + ((x == 0)  ?  (31*SX) : -SX);
    const int s_yp   = s + ((y == 31) ? -(31*SY) : SY);
    const int s_ym   = s + ((y == 0)  ?  (31*SY) : -SY);
    const int s_zp   = s + ((z == 31) ? -(31*SZ) : SZ);
    const int s_tp   = s + ((t == 31) ? -31 : 1);
    const int s_xpyp = s_yp + ((x == 31) ? -(31*SX) : SX);

    const float eta1 = (x & 1) ? -1.f : 1.f;              // (-1)^x0
    const float eta2 = ((x + y) & 1) ? -1.f : 1.f;        // (-1)^(x0+x1)
    const float eta3 = ((x + y + z) & 1) ? -1.f : 1.f;    // (-1)^(x0+x1+x2)

    C3 o[8];          // all 8 channel outputs, stored in one terminal burst
    U9 U; C3 v, g;

    // ch0: identity
    load_vec(xr, xi, 0, s, o[0]);

    // ch1: (0,+1): U0(x) x1(x+xhat), eta0 = 1
    load_U(Urg, Uig, 0, s, U); load_vec(xr, xi, 1, s_xp, v);
    matvec<false>(U, v, 1.f, o[1]);

    // ch2: (1,+1): eta1(x) U1(x) x2(x+yhat)
    load_U(Urg, Uig, 1, s, U); load_vec(xr, xi, 2, s_yp, v);
    matvec<false>(U, v, eta1, o[2]);

    // ch3: (2,+1): eta2(x) U2(x) x3(x+zhat)
    load_U(Urg, Uig, 2, s, U); load_vec(xr, xi, 3, s_zp, v);
    matvec<false>(U, v, eta2, o[3]);

    // ch4: (3,+1): eta3(x) U3(x) x4(x+that)
    load_U(Urg, Uig, 3, s, U); load_vec(xr, xi, 4, s_tp, v);
    matvec<false>(U, v, eta3, o[4]);

    // ch5: (0,-1): U0^dag(x-xhat) x5(x-xhat), eta0 = 1
    load_U(Urg, Uig, 0, s_xm, U); load_vec(xr, xi, 5, s_xm, v);
    matvec<true>(U, v, 1.f, o[5]);

    // ch6: (1,-1): eta1(x-yhat)=eta1(x); U1^dag(x-yhat) x6(x-yhat)
    load_U(Urg, Uig, 1, s_ym, U); load_vec(xr, xi, 6, s_ym, v);
    matvec<true>(U, v, eta1, o[6]);

    // ch7: (0,+1)(1,+1): eta1(x) U1(x) @ U0(x+yhat) @ x7(x+xhat+yhat)
    load_U(Urg, Uig, 0, s_yp, U); load_vec(xr, xi, 7, s_xpyp, v);
    matvec<false>(U, v, 1.f, g);                  // g = U0(x+yhat) x7
    load_U(Urg, Uig, 1, s, U);                    // re-load U1(x) (L2-hot from ch2)
    matvec<false>(U, g, eta1, o[7]);              // y = eta1 * U1(x) g

    // pin the store burst after all loads/compute: main body is read-only,
    // then 48 store-dwords (12 KB/wave) go out back-to-back.
    asm volatile("" ::: "memory");
#pragma unroll
    for (int f = 0; f < 8; ++f) store_out(outr, outi, f, s, o[f]);
}

extern "C" void kernel_launch(void* const* d_in, const int* in_sizes, int n_in,
                              void* d_out, int out_size, void* d_ws, size_t ws_size,
                              hipStream_t stream) {
    const float* xr  = (const float*)d_in[0];
    const float* xi  = (const float*)d_in[1];
    const float* Urg = (const float*)d_in[2];
    const float* Uig = (const float*)d_in[3];
    float* outr = (float*)d_out;
    float* outi = (float*)d_out + (long)8 * V3;   // imag block after real block

    const int block = 256;
    const int grid  = V / block;                  // 4096 blocks
    transport_kernel<<<grid, block, 0, stream>>>(xr, xi, Urg, Uig, outr, outi);
}